// Round 8
// baseline (205.731 us; speedup 1.0000x reference)
//
#include <hip/hip_runtime.h>

// MinEuclideanDistBlock: x(32,8,4096) f32, shapelets(8,128,64) f32 -> out(32,1,128) f32
// out[b,k] = min_w sum_c sqrt( xnorm[b,c,w] + snorm[c,k] - 2*sum_s x[b,c,w+s]*h[c,k,s] )
//
// R7 -> R8 (post-mortem: barrier-paced c-loop structure IS the plateau; R3..R7
// all land 60-67us with all pipes <25% busy):
//  - B resident in REGISTERS: block owns KT=32 k-rows, holds all 8 channels'
//    B-fragments in ~128 VGPRs (loaded once from hbf, no Bs LDS, no per-c barriers).
//  - grid (8 w-chunks x 32 b x 4 k-splits); block sweeps 4 w-tiles of 128.
//    Per tile: 2 barriers around x staging, then unrolled 8-channel burst =
//    64 MFMA + 128 sqrt per barrier interval (4x fatter than R7).
//  - xnorm: per-block LDS table [8][512], fp32 rolling, computed once BEFORE
//    Breg goes live (register-pressure ordering).

typedef short short8 __attribute__((ext_vector_type(8)));
typedef float f32x4 __attribute__((ext_vector_type(4)));

constexpr int Bn = 32, Cn = 8, Ln = 4096, Kn = 128, Sn = 64;
constexpr int Wn = Ln - Sn + 1;          // 4033
constexpr int WT = 128;                  // windows per tile
constexpr int NT = 4;                    // tiles per block -> 512 windows/block
constexpr int NCH = 8;                   // w-chunks (8*512 = 4096 >= Wn)
constexpr int KT = 32;                   // k-rows per block (4 k-splits)
constexpr int BDIM = 256;

__device__ __forceinline__ unsigned int f2bf(float f) {
  unsigned int u = __float_as_uint(f);
  u += 0x7FFFu + ((u >> 16) & 1u);       // round-to-nearest-even
  return u >> 16;
}

// ws layout: [0, 128KB): ushort hbf[C][K][S] = bf16(-2*h);  [128KB, +4KB): float snorm[C][K]
__global__ void prep_kernel(const float* __restrict__ sh,
                            unsigned int* __restrict__ out,
                            unsigned short* __restrict__ hbf,
                            float* __restrict__ snorm) {
  int gid = blockIdx.x * blockDim.x + threadIdx.x;  // 0..4095
  out[gid] = 0x7F7FFFFFu;                           // FLT_MAX bits (Bn*Kn == 4096)
  if (gid < Cn * Kn) {
    const float4* row = (const float4*)(sh + (size_t)gid * Sn);
    uint2* orow = (uint2*)(hbf + (size_t)gid * Sn);
    float a = 0.f;
    #pragma unroll
    for (int i = 0; i < 16; ++i) {
      float4 v = row[i];
      a += v.x * v.x + v.y * v.y + v.z * v.z + v.w * v.w;
      unsigned int p0 = f2bf(-2.f * v.x) | (f2bf(-2.f * v.y) << 16);
      unsigned int p1 = f2bf(-2.f * v.z) | (f2bf(-2.f * v.w) << 16);
      orow[i] = make_uint2(p0, p1);
    }
    snorm[gid] = a;
  }
}

__launch_bounds__(BDIM, 2)
__global__ void med_kernel(const float* __restrict__ x,
                           const unsigned short* __restrict__ hbf,
                           const float* __restrict__ snorm,
                           unsigned int* __restrict__ out) {
  constexpr int XAS = 204;      // u16 per shift-copy (408B)
  constexpr int XCS = 4 * XAS;  // per-channel (4 shifted copies)
  constexpr int XNS = 520;      // xnormAll row stride (floats)
  __shared__ __align__(16) unsigned short Xs[Cn * XCS];   // 13056 B
  __shared__ __align__(16) float xnormAll[Cn * XNS];      // 16640 B

  const int tid  = threadIdx.x;
  const int b    = blockIdx.y;
  const int wch0 = blockIdx.x * (WT * NT);   // 512-window chunk base
  const int kh0  = blockIdx.z * KT;          // k-row base
  const int lane = tid & 63;
  const int wv   = tid >> 6;     // wave 0..3
  const int quad = lane >> 4;    // 0..3
  const int n16  = lane & 15;
  const int wbase = wv * 32;     // wave's window offset in tile

  const float* xb = x + (size_t)b * Cn * Ln;

  // ---- xnorm table for all 512 windows, all channels (fp32 rolling) ----
  // done FIRST so its temporaries die before Breg goes live.
  {
    int c = tid >> 5;
    int wl = (tid & 31) * 16;                // 16 windows per thread
    const float* xc = xb + c * Ln;
    auto xq = [&](int i) -> float {
      float v = (i < Ln) ? xc[i] : 0.f;
      return v * v;
    };
    int w = wch0 + wl;
    float s = 0.f;
    for (int k = 0; k < Sn; ++k) s += xq(w + k);
    xnormAll[c * XNS + wl] = s;
    #pragma unroll
    for (int i = 1; i < 16; ++i) {
      s += xq(w + Sn - 1 + i) - xq(w + i - 1);
      xnormAll[c * XNS + wl + i] = s;
    }
  }

  // ---- B fragments + snorm: registers, all channels, loaded once ----
  short8 Breg[Cn][2][2];   // [c][nt][ks] : 128 VGPRs
  float  snB[Cn][2];
  #pragma unroll
  for (int c = 0; c < Cn; ++c)
    #pragma unroll
    for (int nt = 0; nt < 2; ++nt) {
      int krow = c * Kn + kh0 + nt * 16 + n16;
      snB[c][nt] = snorm[krow];
      #pragma unroll
      for (int ks = 0; ks < 2; ++ks)
        Breg[c][nt][ks] = *(const short8*)(hbf + (size_t)krow * Sn + ks * 32 + quad * 8);
    }

  const int r4  = n16 & 3;
  const int t00 = wbase + (n16 & ~3) + quad * 8;

  float vmin[2] = {3.4e38f, 3.4e38f};

  for (int tile = 0; tile < NT; ++tile) {
    const int w0t = wch0 + tile * WT;
    __syncthreads();  // prev tile's Xs readers done (covers xnormAll writes on tile 0)

    // ---- stage x tile: 4 shifted bf16 copies, all channels ----
    if (tid < 196) {
      const int e = tid;
      #pragma unroll
      for (int c = 0; c < Cn; ++c) {
        float xv = ((w0t + e) < Ln) ? xb[c * Ln + w0t + e] : 0.f;
        unsigned short v = (unsigned short)f2bf(xv);
        #pragma unroll
        for (int r = 0; r < 4; ++r) {
          int t = e - r;
          if (t >= 0) Xs[c * XCS + r * XAS + t] = v;
        }
      }
    }
    __syncthreads();

    float dist[2][2][4] = {};  // [mt][nt][reg] summed over c

    #pragma unroll
    for (int c = 0; c < Cn; ++c) {
      // A fragments: two ds_read_b64 each
      short8 af[2][2];
      #pragma unroll
      for (int mt = 0; mt < 2; ++mt)
        #pragma unroll
        for (int ks = 0; ks < 2; ++ks) {
          const unsigned short* pa = &Xs[c * XCS + r4 * XAS + t00 + mt * 16 + ks * 32];
          uint2 a0 = *(const uint2*)(pa);
          uint2 a1 = *(const uint2*)(pa + 4);
          uint4 q = make_uint4(a0.x, a0.y, a1.x, a1.y);
          af[mt][ks] = __builtin_bit_cast(short8, q);
        }
      float4 xn[2];
      #pragma unroll
      for (int mt = 0; mt < 2; ++mt)
        xn[mt] = *(const float4*)(&xnormAll[c * XNS + tile * WT + wbase + mt * 16 + quad * 4]);

      #pragma unroll
      for (int nt = 0; nt < 2; ++nt)
        #pragma unroll
        for (int mt = 0; mt < 2; ++mt) {
          f32x4 acc;
          #pragma unroll
          for (int rg = 0; rg < 4; ++rg) acc[rg] = xn[mt][rg] + snB[c][nt];
          acc = __builtin_amdgcn_mfma_f32_16x16x32_bf16(af[mt][0], Breg[c][nt][0], acc, 0, 0, 0);
          acc = __builtin_amdgcn_mfma_f32_16x16x32_bf16(af[mt][1], Breg[c][nt][1], acc, 0, 0, 0);
          // acc == d2 (norms in C operand, -2 folded into B)
          #pragma unroll
          for (int rg = 0; rg < 4; ++rg)
            dist[mt][nt][rg] += __builtin_amdgcn_sqrtf(acc[rg]);
        }
    }

    // fold tile into running min (mask invalid windows)
    #pragma unroll
    for (int nt = 0; nt < 2; ++nt)
      #pragma unroll
      for (int mt = 0; mt < 2; ++mt)
        #pragma unroll
        for (int rg = 0; rg < 4; ++rg) {
          int wg = w0t + wbase + mt * 16 + quad * 4 + rg;
          float d = (wg < Wn) ? dist[mt][nt][rg] : 3.4e38f;
          vmin[nt] = fminf(vmin[nt], d);
        }
  }

  // ---- reduce across quads, then global atomicMin ----
  #pragma unroll
  for (int nt = 0; nt < 2; ++nt) {
    float v = vmin[nt];
    v = fminf(v, __shfl_xor(v, 16, 64));
    v = fminf(v, __shfl_xor(v, 32, 64));
    if (lane < 16)
      atomicMin(&out[b * Kn + kh0 + nt * 16 + n16], __float_as_uint(v));
  }
}

extern "C" void kernel_launch(void* const* d_in, const int* in_sizes, int n_in,
                              void* d_out, int out_size, void* d_ws, size_t ws_size,
                              hipStream_t stream) {
  const float* x  = (const float*)d_in[0];
  const float* sh = (const float*)d_in[1];
  unsigned int* out = (unsigned int*)d_out;
  unsigned short* hbf = (unsigned short*)d_ws;                  // 128 KB
  float* snorm = (float*)((char*)d_ws + (size_t)Cn * Kn * Sn * 2);  // +4 KB
  hipLaunchKernelGGL(prep_kernel, dim3(16), dim3(256), 0, stream, sh, out, hbf, snorm);
  hipLaunchKernelGGL(med_kernel, dim3(NCH, Bn, Kn / KT), dim3(BDIM), 0, stream, x, hbf, snorm, out);
}